// Round 3
// baseline (5889.783 us; speedup 1.0000x reference)
//
#include <hip/hip_runtime.h>
#include <cstdint>

#define EPSF 1e-5f

namespace {

constexpr int B  = 32;
constexpr int T0 = 2048, F0 = 20;
constexpr int T1 = 2044, T2 = 2040, T3 = 2034;
constexpr int S1 = 2048;          // stored stride of o1 (pad 2044 -> 2048, mult of 8)
constexpr int S2 = 2040;          // stride of o2/o3/o4 (2040 mult of 8)

// fp16 storage (10-bit mantissa: 8x less rounding error than bf16, same 2B footprint)
__device__ __forceinline__ unsigned short f2h(float f) {
    _Float16 h = (_Float16)f;
    unsigned short u;
    __builtin_memcpy(&u, &h, 2);
    return u;
}
__device__ __forceinline__ float h2f(unsigned short u) {
    _Float16 h;
    __builtin_memcpy(&h, &u, 2);
    return (float)h;
}

// x [B, T0, F0] fp32 -> xT [B, F0, T0] fp16
__global__ __launch_bounds__(256) void transpose_x(const float* __restrict__ x,
                                                   unsigned short* __restrict__ xT)
{
    int idx = blockIdx.x * 256 + threadIdx.x;
    constexpr int total = B * F0 * T0;
    if (idx >= total) return;
    int t = idx % T0;
    int f = (idx / T0) % F0;
    int b = idx / (T0 * F0);
    xT[idx] = f2h(x[((size_t)b * T0 + t) * F0 + f]);
}

// W [O, Cin] -> WT [Cin, O]
__global__ __launch_bounds__(256) void wtrans(const float* __restrict__ W,
                                              float* __restrict__ WT, int O, int Cin)
{
    int idx = blockIdx.x * 256 + threadIdx.x;
    if (idx >= O * Cin) return;
    int o = idx / Cin, i = idx - o * Cin;
    WT[(size_t)i * O + o] = W[idx];
}

// Fold previous layer's BN into next layer's weights; write WT transposed [Cin, O].
// Wf[o,i] = W[o,i]*scale[i/C]; bf[o] = b[o] + sum_i W[o,i]*shift[i/C]
template<int C>
__global__ __launch_bounds__(256) void fold_weights(
    const float* __restrict__ W, const float* __restrict__ bias,
    const float* __restrict__ st, const float* __restrict__ gamma, const float* __restrict__ beta,
    float* __restrict__ WT, float* __restrict__ bf, int O, int F, float invN)
{
    int o = blockIdx.x;
    const int Cin = F * C;
    float local = 0.f;
    for (int i = threadIdx.x; i < Cin; i += 256) {
        int f = i / C;
        float mean = st[f] * invN;
        float var  = st[F + f] * invN - mean * mean;
        float sc = rsqrtf(var + EPSF);
        if (gamma) sc *= gamma[f];
        float sh = (beta ? beta[f] : 0.f) - mean * sc;
        float w = W[(size_t)o * Cin + i];
        WT[(size_t)i * O + o] = w * sc;
        local += w * sh;
    }
#pragma unroll
    for (int d = 32; d; d >>= 1) local += __shfl_down(local, d);
    __shared__ float red[4];
    if ((threadIdx.x & 63) == 0) red[threadIdx.x >> 6] = local;
    __syncthreads();
    if (threadIdx.x == 0) bf[o] = bias[o] + red[0] + red[1] + red[2] + red[3];
}

// per-channel sum & sumsq over (B, t<T): st[f] = sum, st[F+f] = sumsq
__global__ __launch_bounds__(256) void chan_stats(const unsigned short* __restrict__ in,
                                                  float* __restrict__ st, int F, int T, int stride)
{
    int f = blockIdx.x;
    double s = 0.0, q = 0.0;
    for (int b = 0; b < B; ++b) {
        const unsigned short* row = in + ((size_t)b * F + f) * stride;
        for (int t = threadIdx.x; t < T; t += 256) {
            float v = h2f(row[t]);
            s += v; q += (double)v * v;
        }
    }
#pragma unroll
    for (int d = 32; d; d >>= 1) { s += __shfl_down(s, d); q += __shfl_down(q, d); }
    __shared__ double sd[4], qd[4];
    if ((threadIdx.x & 63) == 0) { sd[threadIdx.x >> 6] = s; qd[threadIdx.x >> 6] = q; }
    __syncthreads();
    if (threadIdx.x == 0) {
        st[f]     = (float)(sd[0] + sd[1] + sd[2] + sd[3]);
        st[F + f] = (float)(qd[0] + qd[1] + qd[2] + qd[3]);
    }
}

// Fused splice+conv1x1: out[b,o,t] = act( sum_i WT[i,o] * in[b, i/C, t + (i%C)*offMul] + bias[o] )
// 128x128 tile, BK=32, 256 threads, 8x8 acc per thread (split halves for bank-friendly f4 reads).
// O must be a multiple of 128 here (O=512).
template<int C, int ACT>
__global__ __launch_bounds__(256, 2) void conv128(
    const unsigned short* __restrict__ in, const float* __restrict__ WT,
    const float* __restrict__ bias, unsigned short* __restrict__ out,
    int Fin, int TinStride, int O, int Tout, int OutStride, int offMul)
{
    __shared__ __align__(16) float Ws[32 * 132];   // [kk][oo]
    __shared__ __align__(16) float Is[32 * 132];   // [kk][tt]
    const int Cin = Fin * C;
    const int tid = threadIdx.x;
    const int tx = tid & 15, ty = tid >> 4;
    const int tB = blockIdx.x * 128;
    const int oB = blockIdx.y * 128;
    const int b  = blockIdx.z;
    const unsigned short* inB = in + (size_t)b * Fin * TinStride;

    float acc[8][8] = {};

    for (int iB = 0; iB < Cin; iB += 32) {
#pragma unroll
        for (int p = 0; p < 16; ++p) {             // stage WT: lanes along oo (coalesced, LDS conflict-free)
            int q = p * 256 + tid;
            int kk = q >> 7, oo = q & 127;
            int i = iB + kk;
            Ws[kk * 132 + oo] = (i < Cin) ? WT[(size_t)i * O + oB + oo] : 0.f;
        }
#pragma unroll
        for (int p = 0; p < 16; ++p) {             // stage input: lanes along tt (coalesced, conflict-free)
            int q = p * 256 + tid;
            int kk = q >> 7, tt = q & 127;
            int i = iB + kk;
            int t = tB + tt;
            float v = 0.f;
            if (i < Cin && t < Tout) {
                int f = i / C, c = i - f * C;
                v = h2f(inB[(size_t)f * TinStride + t + c * offMul]);
            }
            Is[kk * 132 + tt] = v;
        }
        __syncthreads();
#pragma unroll 4
        for (int ii = 0; ii < 32; ++ii) {
            const float4 a0 = *(const float4*)&Ws[ii * 132 + ty * 4];
            const float4 a1 = *(const float4*)&Ws[ii * 132 + 64 + ty * 4];
            const float4 b0 = *(const float4*)&Is[ii * 132 + tx * 4];
            const float4 b1 = *(const float4*)&Is[ii * 132 + 64 + tx * 4];
            const float av[8] = { a0.x, a0.y, a0.z, a0.w, a1.x, a1.y, a1.z, a1.w };
            const float bv[8] = { b0.x, b0.y, b0.z, b0.w, b1.x, b1.y, b1.z, b1.w };
#pragma unroll
            for (int u = 0; u < 8; ++u)
#pragma unroll
                for (int v2 = 0; v2 < 8; ++v2)
                    acc[u][v2] = fmaf(av[u], bv[v2], acc[u][v2]);
        }
        __syncthreads();
    }

#pragma unroll
    for (int u = 0; u < 8; ++u) {
        int o = oB + ((u < 4) ? (ty * 4 + u) : (64 + ty * 4 + (u - 4)));
        float bs = bias[o];
        unsigned short* orow = out + ((size_t)b * O + o) * OutStride;
#pragma unroll
        for (int h = 0; h < 2; ++h) {
            int t0 = tB + h * 64 + tx * 4;
            float vals[4];
#pragma unroll
            for (int v = 0; v < 4; ++v) {
                float val = acc[u][h * 4 + v] + bs;
                val = fmaxf(val, 0.f);
                if (ACT == 2) val = fminf(val, 6.f);
                vals[v] = val;
            }
            if (t0 + 3 < Tout) {
                ushort4 pk;
                pk.x = f2h(vals[0]); pk.y = f2h(vals[1]);
                pk.z = f2h(vals[2]); pk.w = f2h(vals[3]);
                *(ushort4*)(orow + t0) = pk;   // 8B aligned: OutStride%8==0, t0%4==0
            } else {
#pragma unroll
                for (int v = 0; v < 4; ++v)
                    if (t0 + v < Tout) orow[t0 + v] = f2h(vals[v]);
            }
        }
    }
}

// L5 conv (1500x512) + relu6 + per-(b,o) sum/sumsq over its T-chunk. Grid: (O/128, B, 4).
__global__ __launch_bounds__(256, 2) void pool128(
    const unsigned short* __restrict__ in, const float* __restrict__ WT,
    const float* __restrict__ bias, float* __restrict__ Sp, float* __restrict__ Qp,
    int Fin, int T, int Tstride, int O)
{
    __shared__ __align__(16) float Ws[32 * 132];
    __shared__ __align__(16) float Is[32 * 132];
    __shared__ float red[128 * 17];
    const int tid = threadIdx.x;
    const int tx = tid & 15, ty = tid >> 4;
    const int oB = blockIdx.x * 128;
    const int b  = blockIdx.y;
    const int z  = blockIdx.z;
    const int t0c = z * 512;
    const int t1c = min(T, t0c + 512);
    const unsigned short* inB = in + (size_t)b * Fin * Tstride;

    float Sl[8] = {}, Ql[8] = {};
    float bs[8];
    int omap[8];
#pragma unroll
    for (int u = 0; u < 8; ++u) {
        int ol = (u < 4) ? (ty * 4 + u) : (64 + ty * 4 + (u - 4));
        omap[u] = ol;
        int o = oB + ol;
        bs[u] = (o < O) ? bias[o] : 0.f;
    }

    for (int tB = t0c; tB < t1c; tB += 128) {
        float acc[8][8] = {};
        for (int iB = 0; iB < Fin; iB += 32) {
#pragma unroll
            for (int p = 0; p < 16; ++p) {
                int q = p * 256 + tid;
                int kk = q >> 7, oo = q & 127;
                Ws[kk * 132 + oo] = (oB + oo < O) ? WT[(size_t)(iB + kk) * O + oB + oo] : 0.f;
            }
#pragma unroll
            for (int p = 0; p < 16; ++p) {
                int q = p * 256 + tid;
                int kk = q >> 7, tt = q & 127;
                int t = tB + tt;
                Is[kk * 132 + tt] = (t < t1c) ? h2f(inB[(size_t)(iB + kk) * Tstride + t]) : 0.f;
            }
            __syncthreads();
#pragma unroll 4
            for (int ii = 0; ii < 32; ++ii) {
                const float4 a0 = *(const float4*)&Ws[ii * 132 + ty * 4];
                const float4 a1 = *(const float4*)&Ws[ii * 132 + 64 + ty * 4];
                const float4 b0 = *(const float4*)&Is[ii * 132 + tx * 4];
                const float4 b1 = *(const float4*)&Is[ii * 132 + 64 + tx * 4];
                const float av[8] = { a0.x, a0.y, a0.z, a0.w, a1.x, a1.y, a1.z, a1.w };
                const float bv[8] = { b0.x, b0.y, b0.z, b0.w, b1.x, b1.y, b1.z, b1.w };
#pragma unroll
                for (int u = 0; u < 8; ++u)
#pragma unroll
                    for (int v2 = 0; v2 < 8; ++v2)
                        acc[u][v2] = fmaf(av[u], bv[v2], acc[u][v2]);
            }
            __syncthreads();
        }
#pragma unroll
        for (int u = 0; u < 8; ++u)
#pragma unroll
            for (int v2 = 0; v2 < 8; ++v2) {
                int t = tB + ((v2 < 4) ? (tx * 4 + v2) : (64 + tx * 4 + (v2 - 4)));
                if (t < t1c) {
                    float val = fminf(fmaxf(acc[u][v2] + bs[u], 0.f), 6.f);
                    Sl[u] += val; Ql[u] += val * val;
                }
            }
    }

#pragma unroll
    for (int u = 0; u < 8; ++u) red[omap[u] * 17 + tx] = Sl[u];
    __syncthreads();
    if (tid < 128) {
        float s = 0.f;
        for (int j = 0; j < 16; ++j) s += red[tid * 17 + j];
        int o = oB + tid;
        if (o < O) Sp[((size_t)z * B + b) * O + o] = s;
    }
    __syncthreads();
#pragma unroll
    for (int u = 0; u < 8; ++u) red[omap[u] * 17 + tx] = Ql[u];
    __syncthreads();
    if (tid < 128) {
        float s = 0.f;
        for (int j = 0; j < 16; ++j) s += red[tid * 17 + j];
        int o = oB + tid;
        if (o < O) Qp[((size_t)z * B + b) * O + o] = s;
    }
}

// bn5 (global over B,T) + per-(b,c) mean/std(ddof=1) -> stat [B, 2*O]
__global__ __launch_bounds__(256) void pool_finalize(
    const float* __restrict__ Sp, const float* __restrict__ Qp,
    const float* __restrict__ g5, const float* __restrict__ b5,
    float* __restrict__ stat, int O, int T)
{
    int co = blockIdx.x * 256 + threadIdx.x;
    if (co >= O) return;
    double sS = 0, sQ = 0;
    for (int z = 0; z < 4; ++z)
        for (int b = 0; b < B; ++b) {
            sS += Sp[((size_t)z * B + b) * O + co];
            sQ += Qp[((size_t)z * B + b) * O + co];
        }
    double invN = 1.0 / ((double)B * T);
    double m = sS * invN;
    double v = sQ * invN - m * m;
    float sc = g5[co] * rsqrtf((float)v + EPSF);
    float sh = b5[co] - (float)m * sc;
    for (int b = 0; b < B; ++b) {
        double sb = 0, qb = 0;
        for (int z = 0; z < 4; ++z) {
            sb += Sp[((size_t)z * B + b) * O + co];
            qb += Qp[((size_t)z * B + b) * O + co];
        }
        double mb = sb / T;
        double vb = (qb - sb * sb / T) / (T - 1);
        if (vb < 0) vb = 0;
        stat[(size_t)b * 2 * O + co]     = (float)mb * sc + sh;
        stat[(size_t)b * 2 * O + O + co] = sqrtf((float)vb) * fabsf(sc);
    }
}

// wave-per-output FC: y[b,o] = relu6( dot(x[b,:], W[o,:]) + bias[o] )
__global__ __launch_bounds__(256) void fc_relu6(const float* __restrict__ x,
                                                const float* __restrict__ W,
                                                const float* __restrict__ bias,
                                                float* __restrict__ y, int Cin, int O)
{
    int wid = (blockIdx.x * 256 + threadIdx.x) >> 6;
    int lane = threadIdx.x & 63;
    if (wid >= B * O) return;
    int b = wid / O, o = wid - b * O;
    const float* xr = x + (size_t)b * Cin;
    const float* wr = W + (size_t)o * Cin;
    float s = 0.f;
    for (int c = lane; c < Cin; c += 64) s = fmaf(xr[c], wr[c], s);
#pragma unroll
    for (int d = 32; d; d >>= 1) s += __shfl_down(s, d);
    if (lane == 0) y[wid] = fminf(fmaxf(s + bias[o], 0.f), 6.f);
}

// BatchNorm over batch dim on [B, O]; thread owns channel o (in-place safe)
__global__ __launch_bounds__(512) void bn_batch(const float* __restrict__ x,
                                                const float* __restrict__ g,
                                                const float* __restrict__ be,
                                                float* __restrict__ y, int O)
{
    int o = threadIdx.x;
    if (o >= O) return;
    float s = 0.f, q = 0.f;
    for (int b = 0; b < B; ++b) { float v = x[b * O + o]; s += v; q += v * v; }
    float m = s / B;
    float var = q / B - m * m;
    float sc = g[o] * rsqrtf(var + EPSF);
    float sh = be[o] - m * sc;
    for (int b = 0; b < B; ++b) y[b * O + o] = x[b * O + o] * sc + sh;
}

} // anonymous namespace

extern "C" void kernel_launch(void* const* d_in, const int* in_sizes, int n_in,
                              void* d_out, int out_size, void* d_ws, size_t ws_size,
                              hipStream_t stream)
{
    (void)in_sizes; (void)n_in; (void)out_size; (void)ws_size;
    const float* x     = (const float*)d_in[0];
    const float* h1_w  = (const float*)d_in[1];
    const float* h1_b  = (const float*)d_in[2];
    const float* h2_w  = (const float*)d_in[3];
    const float* h2_b  = (const float*)d_in[4];
    const float* bn2_g = (const float*)d_in[5];
    const float* bn2_b = (const float*)d_in[6];
    const float* h3_w  = (const float*)d_in[7];
    const float* h3_b  = (const float*)d_in[8];
    const float* bn3_g = (const float*)d_in[9];
    const float* bn3_b = (const float*)d_in[10];
    const float* h4_w  = (const float*)d_in[11];
    const float* h4_b  = (const float*)d_in[12];
    const float* bn4_g = (const float*)d_in[13];
    const float* bn4_b = (const float*)d_in[14];
    const float* h5_w  = (const float*)d_in[15];
    const float* h5_b  = (const float*)d_in[16];
    const float* bn5_g = (const float*)d_in[17];
    const float* bn5_b = (const float*)d_in[18];
    const float* l1_w  = (const float*)d_in[19];
    const float* l1_b  = (const float*)d_in[20];
    const float* bn6_g = (const float*)d_in[21];
    const float* bn6_b = (const float*)d_in[22];
    const float* l2_w  = (const float*)d_in[23];
    const float* l2_b  = (const float*)d_in[24];
    const float* bn7_g = (const float*)d_in[25];
    const float* bn7_b = (const float*)d_in[26];

    char* ws = (char*)d_ws;
    size_t off = 0;
    auto alloc = [&](size_t bytes) {
        char* p = ws + off;
        off += (bytes + 255) & ~(size_t)255;
        return (void*)p;
    };
    unsigned short* xT   = (unsigned short*)alloc((size_t)B * F0 * T0 * 2);
    unsigned short* bufA = (unsigned short*)alloc((size_t)B * 512 * S1 * 2);  // o1 (s=2048), later o3 (s=2040)
    unsigned short* bufB = (unsigned short*)alloc((size_t)B * 512 * S2 * 2);  // o2, later o4 (s=2040)
    float* W1T = (float*)alloc((size_t)100 * 512 * 4);
    float* W2T = (float*)alloc((size_t)1536 * 512 * 4);
    float* W3T = (float*)alloc((size_t)1536 * 512 * 4);
    float* W4T = (float*)alloc((size_t)512 * 512 * 4);
    float* W5T = (float*)alloc((size_t)512 * 1500 * 4);
    float* b2f = (float*)alloc(512 * 4);
    float* b3f = (float*)alloc(512 * 4);
    float* b4f = (float*)alloc(512 * 4);
    float* b5f = (float*)alloc(1500 * 4);
    float* st1 = (float*)alloc(1024 * 4);
    float* st2 = (float*)alloc(1024 * 4);
    float* st3 = (float*)alloc(1024 * 4);
    float* st4 = (float*)alloc(1024 * 4);
    float* Sp  = (float*)alloc((size_t)4 * B * 1500 * 4);
    float* Qp  = (float*)alloc((size_t)4 * B * 1500 * 4);
    float* stat = (float*)alloc((size_t)B * 3000 * 4);
    float* f1  = (float*)alloc((size_t)B * 512 * 4);
    float* f2  = (float*)alloc((size_t)B * 512 * 4);

    transpose_x<<<(B * F0 * T0 + 255) / 256, 256, 0, stream>>>(x, xT);
    wtrans<<<(512 * 100 + 255) / 256, 256, 0, stream>>>(h1_w, W1T, 512, 100);

    // L1: splice(0..4) -> relu(conv 512x100) -> o1 [B,512,2044] (stride 2048)
    conv128<5, 1><<<dim3((T1 + 127) / 128, 4, B), 256, 0, stream>>>(
        xT, W1T, h1_b, bufA, F0, T0, 512, T1, S1, 1);
    chan_stats<<<512, 256, 0, stream>>>(bufA, st1, 512, T1, S1);

    // L2: fold bn1 (no affine); splice(0,2,4) -> relu -> o2 [B,512,2040]
    fold_weights<3><<<512, 256, 0, stream>>>(h2_w, h2_b, st1, nullptr, nullptr,
                                             W2T, b2f, 512, 512, 1.f / (B * T1));
    conv128<3, 1><<<dim3((T2 + 127) / 128, 4, B), 256, 0, stream>>>(
        bufA, W2T, b2f, bufB, 512, S1, 512, T2, S2, 2);
    chan_stats<<<512, 256, 0, stream>>>(bufB, st2, 512, T2, S2);

    // L3: fold bn2; splice(0,3,6) -> relu -> o3 [B,512,2034] (stride 2040)
    fold_weights<3><<<512, 256, 0, stream>>>(h3_w, h3_b, st2, bn2_g, bn2_b,
                                             W3T, b3f, 512, 512, 1.f / (B * T2));
    conv128<3, 1><<<dim3((T3 + 127) / 128, 4, B), 256, 0, stream>>>(
        bufB, W3T, b3f, bufA, 512, S2, 512, T3, S2, 3);
    chan_stats<<<512, 256, 0, stream>>>(bufA, st3, 512, T3, S2);

    // L4: fold bn3; conv 512x512 -> relu6 -> o4 [B,512,2034]
    fold_weights<1><<<512, 256, 0, stream>>>(h4_w, h4_b, st3, bn3_g, bn3_b,
                                             W4T, b4f, 512, 512, 1.f / (B * T3));
    conv128<1, 2><<<dim3((T3 + 127) / 128, 4, B), 256, 0, stream>>>(
        bufA, W4T, b4f, bufB, 512, S2, 512, T3, S2, 0);
    chan_stats<<<512, 256, 0, stream>>>(bufB, st4, 512, T3, S2);

    // L5: fold bn4; conv 1500x512 + relu6 + fused t-chunk reduction (o5 never stored)
    fold_weights<1><<<1500, 256, 0, stream>>>(h5_w, h5_b, st4, bn4_g, bn4_b,
                                              W5T, b5f, 1500, 512, 1.f / (B * T3));
    pool128<<<dim3(12, B, 4), 256, 0, stream>>>(bufB, W5T, b5f, Sp, Qp, 512, T3, S2, 1500);

    // bn5 + stats pooling -> stat [B,3000]
    pool_finalize<<<(1500 + 255) / 256, 256, 0, stream>>>(Sp, Qp, bn5_g, bn5_b, stat, 1500, T3);

    // FC head (wave per output)
    fc_relu6<<<(B * 512 * 64 + 255) / 256, 256, 0, stream>>>(stat, l1_w, l1_b, f1, 3000, 512);
    bn_batch<<<1, 512, 0, stream>>>(f1, bn6_g, bn6_b, f1, 512);
    fc_relu6<<<(B * 512 * 64 + 255) / 256, 256, 0, stream>>>(f1, l2_w, l2_b, f2, 512, 512);
    bn_batch<<<1, 512, 0, stream>>>(f2, bn7_g, bn7_b, (float*)d_out, 512);
}

// Round 4
// 1417.847 us; speedup vs baseline: 4.1540x; 4.1540x over previous
//
#include <hip/hip_runtime.h>
#include <cstdint>

#define EPSF 1e-5f

namespace {

typedef _Float16 f16;
typedef _Float16 v8h __attribute__((ext_vector_type(8)));
typedef float v4f __attribute__((ext_vector_type(4)));

constexpr int B  = 32;
constexpr int T0 = 2048, F0 = 20, F0P = 24;   // input channels padded 20->24 (octet-aligned)
constexpr int T1 = 2044, T2 = 2040, T3 = 2034;

// x [B, T0, F0] fp32 -> xT [B, T0, F0P] fp16 (t-major, zero-padded channels)
__global__ __launch_bounds__(256) void transpose_x(const float* __restrict__ x,
                                                   f16* __restrict__ xT)
{
    int idx = blockIdx.x * 256 + threadIdx.x;
    constexpr int total = B * T0 * F0P;
    if (idx >= total) return;
    int f = idx % F0P;
    int t = (idx / F0P) % T0;
    int b = idx / (F0P * T0);
    float v = (f < F0) ? x[((size_t)b * T0 + t) * F0 + f] : 0.f;
    xT[idx] = (f16)v;
}

// Fold prev-layer BN into weights, cast fp16, reorder K to c-major (k = c*Fp + f).
// Wh[o][k] = W[o][f*C+c] * scale[f]; bf[o] = bias[o] + sum W*shift. st==null -> identity.
__global__ __launch_bounds__(256) void fold_mfma(
    const float* __restrict__ W, const float* __restrict__ bias,
    const float* __restrict__ st, const float* __restrict__ gamma, const float* __restrict__ beta,
    f16* __restrict__ Wh, float* __restrict__ bf,
    int Oreal, int Freal, int Fp, int C, int Cin, int CinOrig, float invN)
{
    int o = blockIdx.x;
    if (o >= Oreal) {                       // zero-pad rows (L5: 1500..1535)
        for (int k = threadIdx.x; k < Cin; k += 256) Wh[(size_t)o * Cin + k] = (f16)0.f;
        if (threadIdx.x == 0) bf[o] = 0.f;
        return;
    }
    float local = 0.f;
    for (int k = threadIdx.x; k < Cin; k += 256) {
        int c = k / Fp, f = k - c * Fp;
        float wv = 0.f;
        if (c < C && f < Freal) {
            float sc = 1.f, sh = 0.f;
            if (st) {
                float mean = st[f] * invN;
                float var  = st[Freal + f] * invN - mean * mean;
                sc = rsqrtf(var + EPSF);
                if (gamma) sc *= gamma[f];
                sh = (beta ? beta[f] : 0.f) - mean * sc;
            }
            float w = W[(size_t)o * CinOrig + f * C + c];
            wv = w * sc;
            local += w * sh;
        }
        Wh[(size_t)o * Cin + k] = (f16)wv;
    }
#pragma unroll
    for (int d = 32; d; d >>= 1) local += __shfl_down(local, d);
    __shared__ float red[4];
    if ((threadIdx.x & 63) == 0) red[threadIdx.x >> 6] = local;
    __syncthreads();
    if (threadIdx.x == 0) bf[o] = bias[o] + red[0] + red[1] + red[2] + red[3];
}

// Fused splice+conv via MFMA. Activations t-major [B][rows][FP-or-512].
// Tile 128(t) x 128(o), BK=32, 4 waves each 64x64 via 4x4 16x16x32 frags.
// A = input (m=t), B = weights (n=o): D col(lane&15)=o, row(quad*4+reg)=t.
template<int ACT, int FP>
__global__ __launch_bounds__(256, 2) void conv_mfma(
    const f16* __restrict__ inT, const f16* __restrict__ Wh,
    const float* __restrict__ bias, f16* __restrict__ outT,
    int TinReal, int Cin, int O, int Tout, int offMul)
{
    __shared__ __align__(16) f16 Ilds[128 * 40];   // [tt][kk] pad 32->40 halves
    __shared__ __align__(16) f16 Wlds[128 * 40];   // [oo][kk]
    const int tid  = threadIdx.x;
    const int lane = tid & 63, wave = tid >> 6;
    const int wt = wave & 1, wo = wave >> 1;
    const int quad = lane >> 4, l16 = lane & 15;
    const int tB = blockIdx.x * 128, oB = blockIdx.y * 128, b = blockIdx.z;
    const f16* inb = inT + (size_t)b * TinReal * FP;
    const int koct = (tid & 3) * 8;
    const int row0 = tid >> 2;

    v4f acc[4][4];
#pragma unroll
    for (int mi = 0; mi < 4; ++mi)
#pragma unroll
        for (int ni = 0; ni < 4; ++ni)
#pragma unroll
            for (int r = 0; r < 4; ++r) acc[mi][ni][r] = 0.f;

    for (int iB = 0; iB < Cin; iB += 32) {
#pragma unroll
        for (int u = 0; u < 2; ++u) {          // stage weights [oo][kk]
            int oo = row0 + u * 64;
            *(v8h*)&Wlds[oo * 40 + koct] =
                *(const v8h*)&Wh[(size_t)(oB + oo) * Cin + iB + koct];
        }
#pragma unroll
        for (int u = 0; u < 2; ++u) {          // stage spliced input [tt][kk]
            int tt = row0 + u * 64;
            int kidx = iB + koct;
            int c = kidx / FP;                 // constant within octet (c-major K)
            int f = kidx - c * FP;
            int t = tB + tt + c * offMul;
            v8h v;
#pragma unroll
            for (int j = 0; j < 8; ++j) v[j] = (f16)0.f;
            if (t < TinReal) v = *(const v8h*)&inb[(size_t)t * FP + f];
            *(v8h*)&Ilds[tt * 40 + koct] = v;
        }
        __syncthreads();
        v8h afr[4], bfr[4];
#pragma unroll
        for (int mi = 0; mi < 4; ++mi)
            afr[mi] = *(const v8h*)&Ilds[(wt * 64 + mi * 16 + l16) * 40 + quad * 8];
#pragma unroll
        for (int ni = 0; ni < 4; ++ni)
            bfr[ni] = *(const v8h*)&Wlds[(wo * 64 + ni * 16 + l16) * 40 + quad * 8];
#pragma unroll
        for (int mi = 0; mi < 4; ++mi)
#pragma unroll
            for (int ni = 0; ni < 4; ++ni)
                acc[mi][ni] = __builtin_amdgcn_mfma_f32_16x16x32_f16(
                    afr[mi], bfr[ni], acc[mi][ni], 0, 0, 0);
        __syncthreads();
    }

#pragma unroll
    for (int ni = 0; ni < 4; ++ni) {
        const int o  = oB + wo * 64 + ni * 16 + l16;
        const float bs = bias[o];
#pragma unroll
        for (int mi = 0; mi < 4; ++mi)
#pragma unroll
            for (int r = 0; r < 4; ++r) {
                int t = tB + wt * 64 + mi * 16 + quad * 4 + r;
                if (t < Tout) {
                    float v = acc[mi][ni][r] + bs;
                    v = fmaxf(v, 0.f);
                    if (ACT == 2) v = fminf(v, 6.f);
                    outT[((size_t)b * Tout + t) * O + o] = (f16)v;
                }
            }
    }
}

// L5: MFMA conv 1536x512 + relu6 + per-(b,o) sum/sumsq over a 512-t chunk.
// Grid (Opad/128, B, 4 chunks). o5 never materialized.
__global__ __launch_bounds__(256, 2) void pool_mfma(
    const f16* __restrict__ inT, const f16* __restrict__ Wh,
    const float* __restrict__ bias, float* __restrict__ Sp, float* __restrict__ Qp,
    int Cin, int T, int Opad)
{
    __shared__ __align__(16) f16 Ilds[128 * 40];
    __shared__ __align__(16) f16 Wlds[128 * 40];
    __shared__ float redS[2][128];
    __shared__ float redQ[2][128];
    const int tid  = threadIdx.x;
    const int lane = tid & 63, wave = tid >> 6;
    const int wt = wave & 1, wo = wave >> 1;
    const int quad = lane >> 4, l16 = lane & 15;
    const int oB = blockIdx.x * 128, b = blockIdx.y, z = blockIdx.z;
    const f16* inb = inT + (size_t)b * T * Cin;
    const int koct = (tid & 3) * 8;
    const int row0 = tid >> 2;

    float Sl[4] = {0, 0, 0, 0}, Ql[4] = {0, 0, 0, 0};
    float bs[4];
#pragma unroll
    for (int ni = 0; ni < 4; ++ni) bs[ni] = bias[oB + wo * 64 + ni * 16 + l16];

    const int tEnd = min(T, z * 512 + 512);
    for (int tB = z * 512; tB < tEnd; tB += 128) {
        v4f acc[4][4];
#pragma unroll
        for (int mi = 0; mi < 4; ++mi)
#pragma unroll
            for (int ni = 0; ni < 4; ++ni)
#pragma unroll
                for (int r = 0; r < 4; ++r) acc[mi][ni][r] = 0.f;

        for (int iB = 0; iB < Cin; iB += 32) {
#pragma unroll
            for (int u = 0; u < 2; ++u) {
                int oo = row0 + u * 64;
                *(v8h*)&Wlds[oo * 40 + koct] =
                    *(const v8h*)&Wh[(size_t)(oB + oo) * Cin + iB + koct];
            }
#pragma unroll
            for (int u = 0; u < 2; ++u) {
                int tt = row0 + u * 64;
                int t = tB + tt;
                v8h v;
#pragma unroll
                for (int j = 0; j < 8; ++j) v[j] = (f16)0.f;
                if (t < T) v = *(const v8h*)&inb[(size_t)t * Cin + iB + koct];
                *(v8h*)&Ilds[tt * 40 + koct] = v;
            }
            __syncthreads();
            v8h afr[4], bfr[4];
#pragma unroll
            for (int mi = 0; mi < 4; ++mi)
                afr[mi] = *(const v8h*)&Ilds[(wt * 64 + mi * 16 + l16) * 40 + quad * 8];
#pragma unroll
            for (int ni = 0; ni < 4; ++ni)
                bfr[ni] = *(const v8h*)&Wlds[(wo * 64 + ni * 16 + l16) * 40 + quad * 8];
#pragma unroll
            for (int mi = 0; mi < 4; ++mi)
#pragma unroll
                for (int ni = 0; ni < 4; ++ni)
                    acc[mi][ni] = __builtin_amdgcn_mfma_f32_16x16x32_f16(
                        afr[mi], bfr[ni], acc[mi][ni], 0, 0, 0);
            __syncthreads();
        }
#pragma unroll
        for (int ni = 0; ni < 4; ++ni)
#pragma unroll
            for (int mi = 0; mi < 4; ++mi)
#pragma unroll
                for (int r = 0; r < 4; ++r) {
                    int t = tB + wt * 64 + mi * 16 + quad * 4 + r;
                    if (t < T) {
                        float v = fminf(fmaxf(acc[mi][ni][r] + bs[ni], 0.f), 6.f);
                        Sl[ni] += v; Ql[ni] += v * v;
                    }
                }
    }

#pragma unroll
    for (int ni = 0; ni < 4; ++ni) {
        float s = Sl[ni], q = Ql[ni];
        s += __shfl_down(s, 32); q += __shfl_down(q, 32);
        s += __shfl_down(s, 16); q += __shfl_down(q, 16);
        if (lane < 16) {
            redS[wt][wo * 64 + ni * 16 + lane] = s;
            redQ[wt][wo * 64 + ni * 16 + lane] = q;
        }
    }
    __syncthreads();
    if (tid < 128) {
        int o = oB + tid;
        Sp[((size_t)z * B + b) * Opad + o] = redS[0][tid] + redS[1][tid];
        Qp[((size_t)z * B + b) * Opad + o] = redQ[0][tid] + redQ[1][tid];
    }
}

// Stats stage 1: per (512-t chunk, b) partial sum/sumsq per channel (F=512, t-major input)
__global__ __launch_bounds__(512) void stats_partial(const f16* __restrict__ inT,
                                                     float* __restrict__ part, int T)
{
    int z = blockIdx.x, b = blockIdx.y, c = threadIdx.x;
    const f16* base = inT + (size_t)b * T * 512;
    float s = 0.f, q = 0.f;
    int t1 = min(T, z * 512 + 512);
    for (int t = z * 512; t < t1; ++t) {
        float v = (float)base[(size_t)t * 512 + c];
        s += v; q += v * v;
    }
    part[(size_t)(z * B + b) * 1024 + c]       = s;
    part[(size_t)(z * B + b) * 1024 + 512 + c] = q;
}

// Stats stage 2: combine 4*B partials -> st[f]=sum, st[512+f]=sumsq
__global__ __launch_bounds__(512) void stats_combine(const float* __restrict__ part,
                                                     float* __restrict__ st)
{
    int c = threadIdx.x;
    double s = 0.0, q = 0.0;
    for (int i = 0; i < 4 * B; ++i) {
        s += part[(size_t)i * 1024 + c];
        q += part[(size_t)i * 1024 + 512 + c];
    }
    st[c] = (float)s;
    st[512 + c] = (float)q;
}

// bn5 (global over B,T) + per-(b,c) mean/std(ddof=1) -> stat [B, 2*Oreal]
__global__ __launch_bounds__(256) void pool_finalize(
    const float* __restrict__ Sp, const float* __restrict__ Qp,
    const float* __restrict__ g5, const float* __restrict__ b5,
    float* __restrict__ stat, int Opad, int Oreal, int T)
{
    int co = blockIdx.x * 256 + threadIdx.x;
    if (co >= Oreal) return;
    double sS = 0, sQ = 0;
    for (int z = 0; z < 4; ++z)
        for (int b = 0; b < B; ++b) {
            sS += Sp[((size_t)z * B + b) * Opad + co];
            sQ += Qp[((size_t)z * B + b) * Opad + co];
        }
    double invN = 1.0 / ((double)B * T);
    double m = sS * invN;
    double v = sQ * invN - m * m;
    float sc = g5[co] * rsqrtf((float)v + EPSF);
    float sh = b5[co] - (float)m * sc;
    for (int b = 0; b < B; ++b) {
        double sb = 0, qb = 0;
        for (int z = 0; z < 4; ++z) {
            sb += Sp[((size_t)z * B + b) * Opad + co];
            qb += Qp[((size_t)z * B + b) * Opad + co];
        }
        double mb = sb / T;
        double vb = (qb - sb * sb / T) / (T - 1);
        if (vb < 0) vb = 0;
        stat[(size_t)b * 2 * Oreal + co]         = (float)mb * sc + sh;
        stat[(size_t)b * 2 * Oreal + Oreal + co] = sqrtf((float)vb) * fabsf(sc);
    }
}

// wave-per-output FC: y[b,o] = relu6( dot(x[b,:], W[o,:]) + bias[o] )
__global__ __launch_bounds__(256) void fc_relu6(const float* __restrict__ x,
                                                const float* __restrict__ W,
                                                const float* __restrict__ bias,
                                                float* __restrict__ y, int Cin, int O)
{
    int wid = (blockIdx.x * 256 + threadIdx.x) >> 6;
    int lane = threadIdx.x & 63;
    if (wid >= B * O) return;
    int b = wid / O, o = wid - b * O;
    const float* xr = x + (size_t)b * Cin;
    const float* wr = W + (size_t)o * Cin;
    float s = 0.f;
    for (int c = lane; c < Cin; c += 64) s = fmaf(xr[c], wr[c], s);
#pragma unroll
    for (int d = 32; d; d >>= 1) s += __shfl_down(s, d);
    if (lane == 0) y[wid] = fminf(fmaxf(s + bias[o], 0.f), 6.f);
}

// BatchNorm over batch dim on [B, O]
__global__ __launch_bounds__(512) void bn_batch(const float* __restrict__ x,
                                                const float* __restrict__ g,
                                                const float* __restrict__ be,
                                                float* __restrict__ y, int O)
{
    int o = threadIdx.x;
    if (o >= O) return;
    float s = 0.f, q = 0.f;
    for (int b = 0; b < B; ++b) { float v = x[b * O + o]; s += v; q += v * v; }
    float m = s / B;
    float var = q / B - m * m;
    float sc = g[o] * rsqrtf(var + EPSF);
    float sh = be[o] - m * sc;
    for (int b = 0; b < B; ++b) y[b * O + o] = x[b * O + o] * sc + sh;
}

} // anonymous namespace

extern "C" void kernel_launch(void* const* d_in, const int* in_sizes, int n_in,
                              void* d_out, int out_size, void* d_ws, size_t ws_size,
                              hipStream_t stream)
{
    (void)in_sizes; (void)n_in; (void)out_size; (void)ws_size;
    const float* x     = (const float*)d_in[0];
    const float* h1_w  = (const float*)d_in[1];
    const float* h1_b  = (const float*)d_in[2];
    const float* h2_w  = (const float*)d_in[3];
    const float* h2_b  = (const float*)d_in[4];
    const float* bn2_g = (const float*)d_in[5];
    const float* bn2_b = (const float*)d_in[6];
    const float* h3_w  = (const float*)d_in[7];
    const float* h3_b  = (const float*)d_in[8];
    const float* bn3_g = (const float*)d_in[9];
    const float* bn3_b = (const float*)d_in[10];
    const float* h4_w  = (const float*)d_in[11];
    const float* h4_b  = (const float*)d_in[12];
    const float* bn4_g = (const float*)d_in[13];
    const float* bn4_b = (const float*)d_in[14];
    const float* h5_w  = (const float*)d_in[15];
    const float* h5_b  = (const float*)d_in[16];
    const float* bn5_g = (const float*)d_in[17];
    const float* bn5_b = (const float*)d_in[18];
    const float* l1_w  = (const float*)d_in[19];
    const float* l1_b  = (const float*)d_in[20];
    const float* bn6_g = (const float*)d_in[21];
    const float* bn6_b = (const float*)d_in[22];
    const float* l2_w  = (const float*)d_in[23];
    const float* l2_b  = (const float*)d_in[24];
    const float* bn7_g = (const float*)d_in[25];
    const float* bn7_b = (const float*)d_in[26];

    char* ws = (char*)d_ws;
    size_t off = 0;
    auto alloc = [&](size_t bytes) {
        char* p = ws + off;
        off += (bytes + 255) & ~(size_t)255;
        return (void*)p;
    };
    f16* xT    = (f16*)alloc((size_t)B * T0 * F0P * 2);
    f16* bufA  = (f16*)alloc((size_t)B * T1 * 512 * 2);   // o1 (2044 rows), later o3 (2034)
    f16* bufB  = (f16*)alloc((size_t)B * T2 * 512 * 2);   // o2 (2040 rows), later o4 (2034)
    f16* Wh1   = (f16*)alloc((size_t)512 * 128 * 2);
    f16* Wh2   = (f16*)alloc((size_t)512 * 1536 * 2);
    f16* Wh3   = (f16*)alloc((size_t)512 * 1536 * 2);
    f16* Wh4   = (f16*)alloc((size_t)512 * 512 * 2);
    f16* Wh5   = (f16*)alloc((size_t)1536 * 512 * 2);
    float* bf1 = (float*)alloc(512 * 4);
    float* bf2 = (float*)alloc(512 * 4);
    float* bf3 = (float*)alloc(512 * 4);
    float* bf4 = (float*)alloc(512 * 4);
    float* bf5 = (float*)alloc(1536 * 4);
    float* st1 = (float*)alloc(1024 * 4);
    float* st2 = (float*)alloc(1024 * 4);
    float* st3 = (float*)alloc(1024 * 4);
    float* st4 = (float*)alloc(1024 * 4);
    float* part = (float*)alloc((size_t)4 * B * 1024 * 4);
    float* Sp  = (float*)alloc((size_t)4 * B * 1536 * 4);
    float* Qp  = (float*)alloc((size_t)4 * B * 1536 * 4);
    float* stat = (float*)alloc((size_t)B * 3000 * 4);
    float* f1  = (float*)alloc((size_t)B * 512 * 4);
    float* f2  = (float*)alloc((size_t)B * 512 * 4);

    transpose_x<<<(B * T0 * F0P + 255) / 256, 256, 0, stream>>>(x, xT);

    // L1: reorder/cast W1 (no prev BN); splice(0..4), C=5, Fp=24, Cin pad->128
    fold_mfma<<<512, 256, 0, stream>>>(h1_w, h1_b, nullptr, nullptr, nullptr,
                                       Wh1, bf1, 512, 20, 24, 5, 128, 100, 0.f);
    conv_mfma<1, 24><<<dim3(16, 4, B), 256, 0, stream>>>(
        xT, Wh1, bf1, bufA, T0, 128, 512, T1, 1);
    stats_partial<<<dim3(4, B), 512, 0, stream>>>(bufA, part, T1);
    stats_combine<<<1, 512, 0, stream>>>(part, st1);

    // L2: fold bn1 (no affine); splice(0,2,4)
    fold_mfma<<<512, 256, 0, stream>>>(h2_w, h2_b, st1, nullptr, nullptr,
                                       Wh2, bf2, 512, 512, 512, 3, 1536, 1536,
                                       1.f / (B * T1));
    conv_mfma<1, 512><<<dim3(16, 4, B), 256, 0, stream>>>(
        bufA, Wh2, bf2, bufB, T1, 1536, 512, T2, 2);
    stats_partial<<<dim3(4, B), 512, 0, stream>>>(bufB, part, T2);
    stats_combine<<<1, 512, 0, stream>>>(part, st2);

    // L3: fold bn2; splice(0,3,6)
    fold_mfma<<<512, 256, 0, stream>>>(h3_w, h3_b, st2, bn2_g, bn2_b,
                                       Wh3, bf3, 512, 512, 512, 3, 1536, 1536,
                                       1.f / (B * T2));
    conv_mfma<1, 512><<<dim3(16, 4, B), 256, 0, stream>>>(
        bufB, Wh3, bf3, bufA, T2, 1536, 512, T3, 3);
    stats_partial<<<dim3(4, B), 512, 0, stream>>>(bufA, part, T3);
    stats_combine<<<1, 512, 0, stream>>>(part, st3);

    // L4: fold bn3; conv 512x512, relu6
    fold_mfma<<<512, 256, 0, stream>>>(h4_w, h4_b, st3, bn3_g, bn3_b,
                                       Wh4, bf4, 512, 512, 512, 1, 512, 512,
                                       1.f / (B * T3));
    conv_mfma<2, 512><<<dim3(16, 4, B), 256, 0, stream>>>(
        bufA, Wh4, bf4, bufB, T3, 512, 512, T3, 0);
    stats_partial<<<dim3(4, B), 512, 0, stream>>>(bufB, part, T3);
    stats_combine<<<1, 512, 0, stream>>>(part, st4);

    // L5: fold bn4; conv 1500(pad 1536)x512 + relu6 + fused t-chunk reduction
    fold_mfma<<<1536, 256, 0, stream>>>(h5_w, h5_b, st4, bn4_g, bn4_b,
                                        Wh5, bf5, 1500, 512, 512, 1, 512, 512,
                                        1.f / (B * T3));
    pool_mfma<<<dim3(12, B, 4), 256, 0, stream>>>(bufB, Wh5, bf5, Sp, Qp, 512, T3, 1536);

    // bn5 + stats pooling -> stat [B,3000]
    pool_finalize<<<6, 256, 0, stream>>>(Sp, Qp, bn5_g, bn5_b, stat, 1536, 1500, T3);

    // FC head
    fc_relu6<<<(B * 512 * 64 + 255) / 256, 256, 0, stream>>>(stat, l1_w, l1_b, f1, 3000, 512);
    bn_batch<<<1, 512, 0, stream>>>(f1, bn6_g, bn6_b, f1, 512);
    fc_relu6<<<(B * 512 * 64 + 255) / 256, 256, 0, stream>>>(f1, l2_w, l2_b, f2, 512, 512);
    bn_batch<<<1, 512, 0, stream>>>(f2, bn7_g, bn7_b, (float*)d_out, 512);
}

// Round 5
// 1040.832 us; speedup vs baseline: 5.6587x; 1.3622x over previous
//
#include <hip/hip_runtime.h>
#include <cstdint>

#define EPSF 1e-5f

namespace {

typedef _Float16 f16;
typedef _Float16 v8h __attribute__((ext_vector_type(8)));
typedef float v4f __attribute__((ext_vector_type(4)));

constexpr int B  = 32;
constexpr int T0 = 2048, F0 = 20, F0P = 24;   // input channels padded 20->24
constexpr int T1 = 2044, T2 = 2040, T3 = 2034;

// async global->LDS DMA, 16B per lane; LDS dest = wave-uniform base + lane*16
__device__ __forceinline__ void gload16(const void* g, void* l) {
    typedef const __attribute__((address_space(1))) void* gp_t;
    typedef __attribute__((address_space(3))) void* lp_t;
    __builtin_amdgcn_global_load_lds((gp_t)(unsigned long long)g,
                                     (lp_t)(unsigned int)(unsigned long long)l,
                                     16, 0, 0);
}

// x [B, T0, F0] fp32 -> xT [B, T0, F0P] fp16 (t-major, zero-padded channels)
__global__ __launch_bounds__(256) void transpose_x(const float* __restrict__ x,
                                                   f16* __restrict__ xT)
{
    int idx = blockIdx.x * 256 + threadIdx.x;
    constexpr int total = B * T0 * F0P;
    if (idx >= total) return;
    int f = idx % F0P;
    int t = (idx / F0P) % T0;
    int b = idx / (F0P * T0);
    float v = (f < F0) ? x[((size_t)b * T0 + t) * F0 + f] : 0.f;
    xT[idx] = (f16)v;
}

// Fold prev-layer BN into weights, cast fp16, reorder K c-major (k = c*Fp + f).
__global__ __launch_bounds__(256) void fold_mfma(
    const float* __restrict__ W, const float* __restrict__ bias,
    const float* __restrict__ st, const float* __restrict__ gamma, const float* __restrict__ beta,
    f16* __restrict__ Wh, float* __restrict__ bf,
    int Oreal, int Freal, int Fp, int C, int Cin, int CinOrig, float invN)
{
    int o = blockIdx.x;
    if (o >= Oreal) {
        for (int k = threadIdx.x; k < Cin; k += 256) Wh[(size_t)o * Cin + k] = (f16)0.f;
        if (threadIdx.x == 0) bf[o] = 0.f;
        return;
    }
    float local = 0.f;
    for (int k = threadIdx.x; k < Cin; k += 256) {
        int c = k / Fp, f = k - c * Fp;
        float wv = 0.f;
        if (c < C && f < Freal) {
            float sc = 1.f, sh = 0.f;
            if (st) {
                float mean = st[f] * invN;
                float var  = st[Freal + f] * invN - mean * mean;
                sc = rsqrtf(var + EPSF);
                if (gamma) sc *= gamma[f];
                sh = (beta ? beta[f] : 0.f) - mean * sc;
            }
            float w = W[(size_t)o * CinOrig + f * C + c];
            wv = w * sc;
            local += w * sh;
        }
        Wh[(size_t)o * Cin + k] = (f16)wv;
    }
#pragma unroll
    for (int d = 32; d; d >>= 1) local += __shfl_down(local, d);
    __shared__ float red[4];
    if ((threadIdx.x & 63) == 0) red[threadIdx.x >> 6] = local;
    __syncthreads();
    if (threadIdx.x == 0) bf[o] = bias[o] + red[0] + red[1] + red[2] + red[3];
}

// Fused splice+conv via MFMA, global_load_lds staging, fused per-channel stats.
// LDS layout [koct][row][8h] -> conflict-free ds_read_b128 fragment reads.
// Grid (16 tB, 4 oB, B). part[SQ][o][slab], slab = tBblk*B + b (512 slabs).
template<int ACT, int FPR>
__global__ __launch_bounds__(256, 3) void conv_mfma(
    const f16* __restrict__ inT, const f16* __restrict__ Wh,
    const float* __restrict__ bias, f16* __restrict__ outT,
    float* __restrict__ partS, float* __restrict__ partQ,
    int Cin, int O, int Tout, int offMul)
{
    __shared__ __align__(16) f16 Ilds[4 * 128 * 8];
    __shared__ __align__(16) f16 Wlds[4 * 128 * 8];
    __shared__ float redS[2][128];
    __shared__ float redQ[2][128];
    const int tid  = threadIdx.x;
    const int lane = tid & 63, wave = tid >> 6;
    const int wt = wave & 1, wo = wave >> 1;
    const int quad = lane >> 4, l16 = lane & 15;
    const int tB = blockIdx.x * 128, oB = blockIdx.y * 128, b = blockIdx.z;
    const f16* inb = inT + (size_t)b * (size_t)FPR *
                     (FPR == 24 ? T0 : (offMul == 2 ? T1 : (offMul == 3 ? T2 : T3)));

    v4f acc[4][4];
#pragma unroll
    for (int mi = 0; mi < 4; ++mi)
#pragma unroll
        for (int ni = 0; ni < 4; ++ni)
#pragma unroll
            for (int r = 0; r < 4; ++r) acc[mi][ni][r] = 0.f;

    for (int iB = 0; iB < Cin; iB += 32) {
#pragma unroll
        for (int j = 0; j < 4; ++j) {          // wave-uniform slab staging
            int s = wave * 4 + j;
            int koct = (s & 7) >> 1, half = s & 1;
            if (s < 8) {
                int kidx = iB + koct * 8;
                int c = kidx / FPR, f = kidx - c * FPR;
                gload16(inb + (size_t)(tB + half * 64 + lane + c * offMul) * FPR + f,
                        &Ilds[(koct * 128 + half * 64) * 8]);
            } else {
                gload16(Wh + (size_t)(oB + half * 64 + lane) * Cin + iB + koct * 8,
                        &Wlds[(koct * 128 + half * 64) * 8]);
            }
        }
        __syncthreads();
        v8h afr[4], bfr[4];
#pragma unroll
        for (int mi = 0; mi < 4; ++mi)
            afr[mi] = *(const v8h*)&Ilds[(quad * 128 + wt * 64 + mi * 16 + l16) * 8];
#pragma unroll
        for (int ni = 0; ni < 4; ++ni)
            bfr[ni] = *(const v8h*)&Wlds[(quad * 128 + wo * 64 + ni * 16 + l16) * 8];
#pragma unroll
        for (int mi = 0; mi < 4; ++mi)
#pragma unroll
            for (int ni = 0; ni < 4; ++ni)
                acc[mi][ni] = __builtin_amdgcn_mfma_f32_16x16x32_f16(
                    afr[mi], bfr[ni], acc[mi][ni], 0, 0, 0);
        __syncthreads();
    }

    float Sl[4] = {0, 0, 0, 0}, Ql[4] = {0, 0, 0, 0};
#pragma unroll
    for (int ni = 0; ni < 4; ++ni) {
        const int o  = oB + wo * 64 + ni * 16 + l16;
        const float bs = bias[o];
#pragma unroll
        for (int mi = 0; mi < 4; ++mi)
#pragma unroll
            for (int r = 0; r < 4; ++r) {
                int t = tB + wt * 64 + mi * 16 + quad * 4 + r;
                if (t < Tout) {
                    float v = acc[mi][ni][r] + bs;
                    v = fmaxf(v, 0.f);
                    if (ACT == 2) v = fminf(v, 6.f);
                    outT[((size_t)b * Tout + t) * O + o] = (f16)v;
                    Sl[ni] += v; Ql[ni] += v * v;
                }
            }
    }
#pragma unroll
    for (int ni = 0; ni < 4; ++ni) {
        float s = Sl[ni], q = Ql[ni];
        s += __shfl_down(s, 32); q += __shfl_down(q, 32);
        s += __shfl_down(s, 16); q += __shfl_down(q, 16);
        if (lane < 16) {
            redS[wt][wo * 64 + ni * 16 + lane] = s;
            redQ[wt][wo * 64 + ni * 16 + lane] = q;
        }
    }
    __syncthreads();
    if (tid < 128) {
        int slab = blockIdx.x * B + b;
        partS[(size_t)(oB + tid) * 512 + slab] = redS[0][tid] + redS[1][tid];
        partQ[(size_t)(oB + tid) * 512 + slab] = redQ[0][tid] + redQ[1][tid];
    }
}

// combine part[o][512 slabs] -> st[o]=sum, st[512+o]=sumsq. Grid 512 blocks.
__global__ __launch_bounds__(256) void stats_combine(const float* __restrict__ pS,
                                                     const float* __restrict__ pQ,
                                                     float* __restrict__ st)
{
    int c = blockIdx.x;
    float s = pS[(size_t)c * 512 + threadIdx.x] + pS[(size_t)c * 512 + 256 + threadIdx.x];
    float q = pQ[(size_t)c * 512 + threadIdx.x] + pQ[(size_t)c * 512 + 256 + threadIdx.x];
#pragma unroll
    for (int d = 32; d; d >>= 1) { s += __shfl_down(s, d); q += __shfl_down(q, d); }
    __shared__ float ss[4], qq[4];
    if ((threadIdx.x & 63) == 0) { ss[threadIdx.x >> 6] = s; qq[threadIdx.x >> 6] = q; }
    __syncthreads();
    if (threadIdx.x == 0) {
        st[c]       = ss[0] + ss[1] + ss[2] + ss[3];
        st[512 + c] = qq[0] + qq[1] + qq[2] + qq[3];
    }
}

// L5: MFMA conv 1536x512 + relu6 + per-(b,o) sum/sumsq over a 512-t chunk.
__global__ __launch_bounds__(256, 3) void pool_mfma(
    const f16* __restrict__ inT, const f16* __restrict__ Wh,
    const float* __restrict__ bias, float* __restrict__ Sp, float* __restrict__ Qp,
    int Cin, int T, int Opad)
{
    __shared__ __align__(16) f16 Ilds[4 * 128 * 8];
    __shared__ __align__(16) f16 Wlds[4 * 128 * 8];
    __shared__ float redS[2][128];
    __shared__ float redQ[2][128];
    const int tid  = threadIdx.x;
    const int lane = tid & 63, wave = tid >> 6;
    const int wt = wave & 1, wo = wave >> 1;
    const int quad = lane >> 4, l16 = lane & 15;
    const int oB = blockIdx.x * 128, b = blockIdx.y, z = blockIdx.z;
    const f16* inb = inT + (size_t)b * T * Cin;

    float Sl[4] = {0, 0, 0, 0}, Ql[4] = {0, 0, 0, 0};
    float bs[4];
#pragma unroll
    for (int ni = 0; ni < 4; ++ni) bs[ni] = bias[oB + wo * 64 + ni * 16 + l16];

    const int tEnd = min(T, z * 512 + 512);
    for (int tB = z * 512; tB < tEnd; tB += 128) {
        v4f acc[4][4];
#pragma unroll
        for (int mi = 0; mi < 4; ++mi)
#pragma unroll
            for (int ni = 0; ni < 4; ++ni)
#pragma unroll
                for (int r = 0; r < 4; ++r) acc[mi][ni][r] = 0.f;

        for (int iB = 0; iB < Cin; iB += 32) {
#pragma unroll
            for (int j = 0; j < 4; ++j) {
                int s = wave * 4 + j;
                int koct = (s & 7) >> 1, half = s & 1;
                if (s < 8) {
                    gload16(inb + (size_t)(tB + half * 64 + lane) * Cin + iB + koct * 8,
                            &Ilds[(koct * 128 + half * 64) * 8]);
                } else {
                    gload16(Wh + (size_t)(oB + half * 64 + lane) * Cin + iB + koct * 8,
                            &Wlds[(koct * 128 + half * 64) * 8]);
                }
            }
            __syncthreads();
            v8h afr[4], bfr[4];
#pragma unroll
            for (int mi = 0; mi < 4; ++mi)
                afr[mi] = *(const v8h*)&Ilds[(quad * 128 + wt * 64 + mi * 16 + l16) * 8];
#pragma unroll
            for (int ni = 0; ni < 4; ++ni)
                bfr[ni] = *(const v8h*)&Wlds[(quad * 128 + wo * 64 + ni * 16 + l16) * 8];
#pragma unroll
            for (int mi = 0; mi < 4; ++mi)
#pragma unroll
                for (int ni = 0; ni < 4; ++ni)
                    acc[mi][ni] = __builtin_amdgcn_mfma_f32_16x16x32_f16(
                        afr[mi], bfr[ni], acc[mi][ni], 0, 0, 0);
            __syncthreads();
        }
#pragma unroll
        for (int ni = 0; ni < 4; ++ni)
#pragma unroll
            for (int mi = 0; mi < 4; ++mi)
#pragma unroll
                for (int r = 0; r < 4; ++r) {
                    int t = tB + wt * 64 + mi * 16 + quad * 4 + r;
                    if (t < T) {
                        float v = fminf(fmaxf(acc[mi][ni][r] + bs[ni], 0.f), 6.f);
                        Sl[ni] += v; Ql[ni] += v * v;
                    }
                }
    }

#pragma unroll
    for (int ni = 0; ni < 4; ++ni) {
        float s = Sl[ni], q = Ql[ni];
        s += __shfl_down(s, 32); q += __shfl_down(q, 32);
        s += __shfl_down(s, 16); q += __shfl_down(q, 16);
        if (lane < 16) {
            redS[wt][wo * 64 + ni * 16 + lane] = s;
            redQ[wt][wo * 64 + ni * 16 + lane] = q;
        }
    }
    __syncthreads();
    if (tid < 128) {
        int o = oB + tid;
        Sp[((size_t)z * B + b) * Opad + o] = redS[0][tid] + redS[1][tid];
        Qp[((size_t)z * B + b) * Opad + o] = redQ[0][tid] + redQ[1][tid];
    }
}

// bn5 (global over B,T) + per-(b,c) mean/std(ddof=1) -> stat [B, 2*Oreal]
__global__ __launch_bounds__(256) void pool_finalize(
    const float* __restrict__ Sp, const float* __restrict__ Qp,
    const float* __restrict__ g5, const float* __restrict__ b5,
    float* __restrict__ stat, int Opad, int Oreal, int T)
{
    int co = blockIdx.x * 256 + threadIdx.x;
    if (co >= Oreal) return;
    double sS = 0, sQ = 0;
    for (int z = 0; z < 4; ++z)
        for (int b = 0; b < B; ++b) {
            sS += Sp[((size_t)z * B + b) * Opad + co];
            sQ += Qp[((size_t)z * B + b) * Opad + co];
        }
    double invN = 1.0 / ((double)B * T);
    double m = sS * invN;
    double v = sQ * invN - m * m;
    float sc = g5[co] * rsqrtf((float)v + EPSF);
    float sh = b5[co] - (float)m * sc;
    for (int b = 0; b < B; ++b) {
        double sb = 0, qb = 0;
        for (int z = 0; z < 4; ++z) {
            sb += Sp[((size_t)z * B + b) * Opad + co];
            qb += Qp[((size_t)z * B + b) * Opad + co];
        }
        double mb = sb / T;
        double vb = (qb - sb * sb / T) / (T - 1);
        if (vb < 0) vb = 0;
        stat[(size_t)b * 2 * Oreal + co]         = (float)mb * sc + sh;
        stat[(size_t)b * 2 * Oreal + Oreal + co] = sqrtf((float)vb) * fabsf(sc);
    }
}

// wave-per-output FC: y[b,o] = relu6( dot(x[b,:], W[o,:]) + bias[o] )
__global__ __launch_bounds__(256) void fc_relu6(const float* __restrict__ x,
                                                const float* __restrict__ W,
                                                const float* __restrict__ bias,
                                                float* __restrict__ y, int Cin, int O)
{
    int wid = (blockIdx.x * 256 + threadIdx.x) >> 6;
    int lane = threadIdx.x & 63;
    if (wid >= B * O) return;
    int b = wid / O, o = wid - b * O;
    const float* xr = x + (size_t)b * Cin;
    const float* wr = W + (size_t)o * Cin;
    float s = 0.f;
    for (int c = lane; c < Cin; c += 64) s = fmaf(xr[c], wr[c], s);
#pragma unroll
    for (int d = 32; d; d >>= 1) s += __shfl_down(s, d);
    if (lane == 0) y[wid] = fminf(fmaxf(s + bias[o], 0.f), 6.f);
}

// BatchNorm over batch dim on [B, O]
__global__ __launch_bounds__(512) void bn_batch(const float* __restrict__ x,
                                                const float* __restrict__ g,
                                                const float* __restrict__ be,
                                                float* __restrict__ y, int O)
{
    int o = threadIdx.x;
    if (o >= O) return;
    float s = 0.f, q = 0.f;
    for (int b = 0; b < B; ++b) { float v = x[b * O + o]; s += v; q += v * v; }
    float m = s / B;
    float var = q / B - m * m;
    float sc = g[o] * rsqrtf(var + EPSF);
    float sh = be[o] - m * sc;
    for (int b = 0; b < B; ++b) y[b * O + o] = x[b * O + o] * sc + sh;
}

} // anonymous namespace

extern "C" void kernel_launch(void* const* d_in, const int* in_sizes, int n_in,
                              void* d_out, int out_size, void* d_ws, size_t ws_size,
                              hipStream_t stream)
{
    (void)in_sizes; (void)n_in; (void)out_size; (void)ws_size;
    const float* x     = (const float*)d_in[0];
    const float* h1_w  = (const float*)d_in[1];
    const float* h1_b  = (const float*)d_in[2];
    const float* h2_w  = (const float*)d_in[3];
    const float* h2_b  = (const float*)d_in[4];
    const float* bn2_g = (const float*)d_in[5];
    const float* bn2_b = (const float*)d_in[6];
    const float* h3_w  = (const float*)d_in[7];
    const float* h3_b  = (const float*)d_in[8];
    const float* bn3_g = (const float*)d_in[9];
    const float* bn3_b = (const float*)d_in[10];
    const float* h4_w  = (const float*)d_in[11];
    const float* h4_b  = (const float*)d_in[12];
    const float* bn4_g = (const float*)d_in[13];
    const float* bn4_b = (const float*)d_in[14];
    const float* h5_w  = (const float*)d_in[15];
    const float* h5_b  = (const float*)d_in[16];
    const float* bn5_g = (const float*)d_in[17];
    const float* bn5_b = (const float*)d_in[18];
    const float* l1_w  = (const float*)d_in[19];
    const float* l1_b  = (const float*)d_in[20];
    const float* bn6_g = (const float*)d_in[21];
    const float* bn6_b = (const float*)d_in[22];
    const float* l2_w  = (const float*)d_in[23];
    const float* l2_b  = (const float*)d_in[24];
    const float* bn7_g = (const float*)d_in[25];
    const float* bn7_b = (const float*)d_in[26];

    char* ws = (char*)d_ws;
    size_t off = 0;
    auto alloc = [&](size_t bytes) {
        char* p = ws + off;
        off += (bytes + 255) & ~(size_t)255;
        return (void*)p;
    };
    f16* xT    = (f16*)alloc(((size_t)B * T0 + 64) * F0P * 2);
    f16* bufA  = (f16*)alloc(((size_t)B * T1 + 64) * 512 * 2);  // o1, later o3
    f16* bufB  = (f16*)alloc(((size_t)B * T2 + 64) * 512 * 2);  // o2, later o4
    f16* Wh1   = (f16*)alloc((size_t)512 * 128 * 2);
    f16* Wh2   = (f16*)alloc((size_t)512 * 1536 * 2);
    f16* Wh3   = (f16*)alloc((size_t)512 * 1536 * 2);
    f16* Wh4   = (f16*)alloc((size_t)512 * 512 * 2);
    f16* Wh5   = (f16*)alloc((size_t)1536 * 512 * 2);
    float* bf1 = (float*)alloc(512 * 4);
    float* bf2 = (float*)alloc(512 * 4);
    float* bf3 = (float*)alloc(512 * 4);
    float* bf4 = (float*)alloc(512 * 4);
    float* bf5 = (float*)alloc(1536 * 4);
    float* st1 = (float*)alloc(1024 * 4);
    float* st2 = (float*)alloc(1024 * 4);
    float* st3 = (float*)alloc(1024 * 4);
    float* st4 = (float*)alloc(1024 * 4);
    float* pS  = (float*)alloc((size_t)512 * 512 * 4);
    float* pQ  = (float*)alloc((size_t)512 * 512 * 4);
    float* Sp  = (float*)alloc((size_t)4 * B * 1536 * 4);
    float* Qp  = (float*)alloc((size_t)4 * B * 1536 * 4);
    float* stat = (float*)alloc((size_t)B * 3000 * 4);
    float* f1  = (float*)alloc((size_t)B * 512 * 4);
    float* f2  = (float*)alloc((size_t)B * 512 * 4);

    transpose_x<<<(B * T0 * F0P + 255) / 256, 256, 0, stream>>>(x, xT);

    // L1: reorder/cast W1 (no prev BN); splice(0..4), Cin pad->128
    fold_mfma<<<512, 256, 0, stream>>>(h1_w, h1_b, nullptr, nullptr, nullptr,
                                       Wh1, bf1, 512, 20, 24, 5, 128, 100, 0.f);
    conv_mfma<1, 24><<<dim3(16, 4, B), 256, 0, stream>>>(
        xT, Wh1, bf1, bufA, pS, pQ, 128, 512, T1, 1);
    stats_combine<<<512, 256, 0, stream>>>(pS, pQ, st1);

    // L2: fold bn1 (no affine); splice(0,2,4)
    fold_mfma<<<512, 256, 0, stream>>>(h2_w, h2_b, st1, nullptr, nullptr,
                                       Wh2, bf2, 512, 512, 512, 3, 1536, 1536,
                                       1.f / (B * T1));
    conv_mfma<1, 512><<<dim3(16, 4, B), 256, 0, stream>>>(
        bufA, Wh2, bf2, bufB, pS, pQ, 1536, 512, T2, 2);
    stats_combine<<<512, 256, 0, stream>>>(pS, pQ, st2);

    // L3: fold bn2; splice(0,3,6)
    fold_mfma<<<512, 256, 0, stream>>>(h3_w, h3_b, st2, bn2_g, bn2_b,
                                       Wh3, bf3, 512, 512, 512, 3, 1536, 1536,
                                       1.f / (B * T2));
    conv_mfma<1, 512><<<dim3(16, 4, B), 256, 0, stream>>>(
        bufB, Wh3, bf3, bufA, pS, pQ, 1536, 512, T3, 3);
    stats_combine<<<512, 256, 0, stream>>>(pS, pQ, st3);

    // L4: fold bn3; conv 512x512, relu6
    fold_mfma<<<512, 256, 0, stream>>>(h4_w, h4_b, st3, bn3_g, bn3_b,
                                       Wh4, bf4, 512, 512, 512, 1, 512, 512,
                                       1.f / (B * T3));
    conv_mfma<2, 512><<<dim3(16, 4, B), 256, 0, stream>>>(
        bufA, Wh4, bf4, bufB, pS, pQ, 512, 512, T3, 0);
    stats_combine<<<512, 256, 0, stream>>>(pS, pQ, st4);

    // L5: fold bn4; conv 1500(pad 1536)x512 + relu6 + fused t-chunk reduction
    fold_mfma<<<1536, 256, 0, stream>>>(h5_w, h5_b, st4, bn4_g, bn4_b,
                                        Wh5, bf5, 1500, 512, 512, 1, 512, 512,
                                        1.f / (B * T3));
    pool_mfma<<<dim3(12, B, 4), 256, 0, stream>>>(bufB, Wh5, bf5, Sp, Qp, 512, T3, 1536);

    // bn5 + stats pooling -> stat [B,3000]
    pool_finalize<<<6, 256, 0, stream>>>(Sp, Qp, bn5_g, bn5_b, stat, 1536, 1500, T3);

    // FC head
    fc_relu6<<<(B * 512 * 64 + 255) / 256, 256, 0, stream>>>(stat, l1_w, l1_b, f1, 3000, 512);
    bn_batch<<<1, 512, 0, stream>>>(f1, bn6_g, bn6_b, f1, 512);
    fc_relu6<<<(B * 512 * 64 + 255) / 256, 256, 0, stream>>>(f1, l2_w, l2_b, f2, 512, 512);
    bn_batch<<<1, 512, 0, stream>>>(f2, bn7_g, bn7_b, (float*)d_out, 512);
}